// Round 1
// 153.018 us; speedup vs baseline: 1.0756x; 1.0756x over previous
//
#include <hip/hip_runtime.h>
#include <hip/hip_bf16.h>

typedef __attribute__((ext_vector_type(8))) short short8;
typedef __attribute__((ext_vector_type(4))) short short4v;
typedef __attribute__((ext_vector_type(4))) float floatx4;

#define BDIM 128
#define RDIM 1024
#define NB   4096
#define NG   16

__device__ __forceinline__ float mishf(float x) {
    float e = __expf(x);
    float t = e * (e + 2.0f);
    float r = x * (t / (t + 2.0f));
    return x > 20.0f ? x : r;
}

__device__ __forceinline__ short8 cvt8v(float4 f0, float4 f1) {
    union { __hip_bfloat162 h; unsigned u; } c0, c1, c2, c3;
    c0.h = __float22bfloat162_rn(make_float2(f0.x, f0.y));
    c1.h = __float22bfloat162_rn(make_float2(f0.z, f0.w));
    c2.h = __float22bfloat162_rn(make_float2(f1.x, f1.y));
    c3.h = __float22bfloat162_rn(make_float2(f1.z, f1.w));
    union { short8 s; unsigned u[4]; } r;
    r.u[0] = c0.u; r.u[1] = c1.u; r.u[2] = c2.u; r.u[3] = c3.u;
    return r.s;
}

__device__ __forceinline__ short4v cvt4v(float4 f) {
    union { __hip_bfloat162 h; unsigned u; } c0, c1;
    c0.h = __float22bfloat162_rn(make_float2(f.x, f.y));
    c1.h = __float22bfloat162_rn(make_float2(f.z, f.w));
    union { short4v s; unsigned u[2]; } r;
    r.u[0] = c0.u; r.u[1] = c1.u;
    return r.s;
}

// async global->LDS, 16B per lane, LDS dest = wave-uniform base + lane*16
__device__ __forceinline__ void gld16(const void* g, void* l) {
    __builtin_amdgcn_global_load_lds(
        (const __attribute__((address_space(1))) unsigned int*)g,
        (__attribute__((address_space(3))) unsigned int*)l, 16, 0, 0);
}

#define MFMA(a, b, c) __builtin_amdgcn_mfma_f32_16x16x32_bf16(a, b, c, 0, 0, 0)

// region sizes (floats) for the flat conversion pass
#define RF_N     4194304u   // 4096*1024
#define C1       4194304u
#define C2       5242880u   // +Wrfrf 1024*1024
#define C3       5373952u   // +Wrfbb 128*1024
#define C4       5505024u   // +Wbbrf 1024*128
#define CT       5521408u   // +Wbbbb 128*128

// ---------------- prep: BB mean + one-time fp32->bf16 of all GEMM operands ----------------
__global__ void __launch_bounds__(256) k_prep(
    const float* __restrict__ bb, const float* __restrict__ rf,
    const float* __restrict__ Wrfrf, const float* __restrict__ Wrfbb,
    const float* __restrict__ Wbbrf, const float* __restrict__ Wbbbb,
    short* __restrict__ bb_b, short* __restrict__ mean_b, short* __restrict__ rf_b,
    short* __restrict__ wrfrf_b, short* __restrict__ wrfbb_b,
    short* __restrict__ wbbrf_b, short* __restrict__ wbbbb_b)
{
    int bid = blockIdx.x;
    int tid = threadIdx.x;
    if (bid < 512) {
        // mean over G + bf16 copy of BB
        int b = bid * 8 + (tid >> 5);
        int d = (tid & 31) * 4;
        const float4* p = (const float4*)(bb + (size_t)b * (NG * BDIM) + d);
        short* ob = bb_b + (size_t)b * (NG * BDIM) + d;
        float4 s = {0.f, 0.f, 0.f, 0.f};
        #pragma unroll
        for (int g = 0; g < NG; ++g) {
            float4 v = p[g * (BDIM / 4)];
            s.x += v.x; s.y += v.y; s.z += v.z; s.w += v.w;
            *(short4v*)(ob + g * BDIM) = cvt4v(v);
        }
        s.x *= 0.0625f; s.y *= 0.0625f; s.z *= 0.0625f; s.w *= 0.0625f;
        *(short4v*)(mean_b + (size_t)b * BDIM + d) = cvt4v(s);
    } else {
        // flat fp32->bf16 over RF + 4 weights (all region sizes multiples of 8)
        size_t t = (size_t)(bid - 512) * 256 + tid;
        for (size_t base = t * 8; base < CT; base += (size_t)512 * 256 * 8) {
            const float* s; short* dst; size_t off;
            if (base < C1)      { s = rf;    dst = rf_b;    off = base; }
            else if (base < C2) { s = Wrfrf; dst = wrfrf_b; off = base - C1; }
            else if (base < C3) { s = Wrfbb; dst = wrfbb_b; off = base - C2; }
            else if (base < C4) { s = Wbbrf; dst = wbbrf_b; off = base - C3; }
            else                { s = Wbbbb; dst = wbbbb_b; off = base - C4; }
            float4 f0 = ((const float4*)(s + off))[0];
            float4 f1 = ((const float4*)(s + off))[1];
            *(short8*)(dst + off) = cvt8v(f0, f1);
        }
    }
}

// ---- new_RF = mish(RF@Wrfrf^T+b1) + mish(mean@Wbbrf^T+b2); rf2bb = mish(RF@Wrfbb^T+b3) ----
// 512 blocks x 256 thr; tile 128(M)x64(N), BK=64, dbuf, global_load_lds staging,
// XOR-swizzled LDS (slot ^= row&7, pre-applied on the per-lane global source).
__global__ void __launch_bounds__(256) k_newrf(
    const short* __restrict__ rfb,     // [4096,1024] bf16
    const short* __restrict__ meanb,   // [4096,128]  bf16
    const short* __restrict__ wrfrfb,  // [1024,1024] bf16
    const float* __restrict__ brfrf,
    const short* __restrict__ wbbrfb,  // [1024,128]  bf16
    const float* __restrict__ bbbrf,
    const short* __restrict__ wrfbbb,  // [128,1024]  bf16
    const float* __restrict__ brfbb,
    float* __restrict__ out,           // [4096,1024]
    float* __restrict__ rf2bb)         // [4096,128] fp32 ws
{
    __shared__ alignas(16) short As[2][128 * 64];
    __shared__ alignas(16) short Bs[2][64 * 64];
    __shared__ alignas(16) short Ws2[2][16 * 64];
    int tid = threadIdx.x;
    int wave = tid >> 6, lane = tid & 63;
    int r = lane & 15, quad = lane >> 4;
    int wm = (wave & 1) * 64, wn = (wave >> 1) * 32;
    int mt = blockIdx.x >> 4, nt = blockIdx.x & 15;
    int m0 = mt * 128, n0 = nt * 64;
    bool doP = (nt < 8);

    // staging lane decomposition: 1 issue = 64 lanes x 16B = 8 rows of 128B
    int srow = lane >> 3;                 // row within 8-row group
    int scol = ((lane & 7) ^ srow) * 8;   // pre-swizzled source column (elements)

    const short* aB = rfb    + (size_t)(m0 + wave * 32 + srow) * RDIM + scol;
    const short* bB = wrfrfb + (size_t)(n0 + wave * 16 + srow) * RDIM + scol;
    const short* wB = wrfbbb + (size_t)(nt * 16 + srow) * RDIM + scol;

    floatx4 acc1[4][2], acc2[4][2], acc3[4];
    #pragma unroll
    for (int mi = 0; mi < 4; ++mi) {
        acc1[mi][0] = floatx4{0.f,0.f,0.f,0.f}; acc1[mi][1] = acc1[mi][0];
        acc2[mi][0] = acc1[mi][0]; acc2[mi][1] = acc1[mi][0];
        acc3[mi] = acc1[mi][0];
    }

    auto stage1 = [&](int buf, int k) {
        #pragma unroll
        for (int j = 0; j < 4; ++j)
            gld16(aB + (size_t)j * 8 * RDIM + k, &As[buf][(wave * 32 + j * 8) * 64]);
        #pragma unroll
        for (int j = 0; j < 2; ++j)
            gld16(bB + (size_t)j * 8 * RDIM + k, &Bs[buf][(wave * 16 + j * 8) * 64]);
        if (doP && wave == 0) {
            #pragma unroll
            for (int j = 0; j < 2; ++j)
                gld16(wB + (size_t)j * 8 * RDIM + k, &Ws2[buf][j * 8 * 64]);
        }
    };

    stage1(0, 0);
    __syncthreads();

    for (int it = 0; it < 16; ++it) {
        int buf = it & 1;
        if (it < 15) stage1(buf ^ 1, (it + 1) * 64);
        const short* Ac = As[buf];
        const short* Bc = Bs[buf];
        const short* Wc = Ws2[buf];
        #pragma unroll
        for (int kk = 0; kk < 2; ++kk) {
            int sw = (((kk << 2) + quad) ^ (r & 7)) << 3;
            short8 af[4];
            #pragma unroll
            for (int mi = 0; mi < 4; ++mi)
                af[mi] = *(const short8*)&Ac[(wm + mi * 16 + r) * 64 + sw];
            short8 bf0 = *(const short8*)&Bc[(wn + r) * 64 + sw];
            short8 bf1 = *(const short8*)&Bc[(wn + 16 + r) * 64 + sw];
            #pragma unroll
            for (int mi = 0; mi < 4; ++mi) {
                acc1[mi][0] = MFMA(af[mi], bf0, acc1[mi][0]);
                acc1[mi][1] = MFMA(af[mi], bf1, acc1[mi][1]);
            }
            if (doP && (wave & 2) == 0) {
                short8 b2 = *(const short8*)&Wc[r * 64 + sw];
                #pragma unroll
                for (int mi = 0; mi < 4; ++mi) acc3[mi] = MFMA(af[mi], b2, acc3[mi]);
            }
        }
        __syncthreads();
    }

    // ---- GEMM2: mean @ Wbbrf^T, K=128 (2 iters of BK=64) ----
    const short* a2B = meanb  + (size_t)(m0 + wave * 32 + srow) * BDIM + scol;
    const short* b2B = wbbrfb + (size_t)(n0 + wave * 16 + srow) * BDIM + scol;
    auto stage2 = [&](int buf, int k) {
        #pragma unroll
        for (int j = 0; j < 4; ++j)
            gld16(a2B + (size_t)j * 8 * BDIM + k, &As[buf][(wave * 32 + j * 8) * 64]);
        #pragma unroll
        for (int j = 0; j < 2; ++j)
            gld16(b2B + (size_t)j * 8 * BDIM + k, &Bs[buf][(wave * 16 + j * 8) * 64]);
    };
    stage2(0, 0);
    __syncthreads();
    for (int it = 0; it < 2; ++it) {
        int buf = it & 1;
        if (it < 1) stage2(1, 64);
        const short* Ac = As[buf];
        const short* Bc = Bs[buf];
        #pragma unroll
        for (int kk = 0; kk < 2; ++kk) {
            int sw = (((kk << 2) + quad) ^ (r & 7)) << 3;
            short8 af[4];
            #pragma unroll
            for (int mi = 0; mi < 4; ++mi)
                af[mi] = *(const short8*)&Ac[(wm + mi * 16 + r) * 64 + sw];
            short8 bf0 = *(const short8*)&Bc[(wn + r) * 64 + sw];
            short8 bf1 = *(const short8*)&Bc[(wn + 16 + r) * 64 + sw];
            #pragma unroll
            for (int mi = 0; mi < 4; ++mi) {
                acc2[mi][0] = MFMA(af[mi], bf0, acc2[mi][0]);
                acc2[mi][1] = MFMA(af[mi], bf1, acc2[mi][1]);
            }
        }
        __syncthreads();
    }

    // ---- epilogue (unchanged math) ----
    #pragma unroll
    for (int nj = 0; nj < 2; ++nj) {
        int col = n0 + wn + nj * 16 + r;
        float b1 = brfrf[col];
        float b2 = bbbrf[col];
        #pragma unroll
        for (int mi = 0; mi < 4; ++mi) {
            #pragma unroll
            for (int g = 0; g < 4; ++g) {
                int row = m0 + wm + mi * 16 + quad * 4 + g;
                out[(size_t)row * RDIM + col] =
                    mishf(acc1[mi][nj][g] + b1) + mishf(acc2[mi][nj][g] + b2);
            }
        }
    }
    if (doP && (wave & 2) == 0) {
        int col = nt * 16 + r;
        float bs = brfbb[col];
        #pragma unroll
        for (int mi = 0; mi < 4; ++mi) {
            #pragma unroll
            for (int g = 0; g < 4; ++g) {
                int row = m0 + wm + mi * 16 + quad * 4 + g;
                rf2bb[(size_t)row * BDIM + col] = mishf(acc3[mi][g] + bs);
            }
        }
    }
}

// ---------------- new_BB = mish(BB @ W_bbbb^T + b) + rf2bb[b] ----------------
// 512 blocks x 256 thr; bf16 inputs, full 128x128 A + W staged once via global_load_lds
// with XOR swizzle; one barrier total; 64 MFMAs/wave.
__global__ void __launch_bounds__(256) k_newbb(
    const short* __restrict__ bbb,   // [65536,128] bf16
    const short* __restrict__ wb,    // [128,128]   bf16
    const float* __restrict__ bias,  // [128]
    const float* __restrict__ rf2bb, // [4096,128]  fp32
    float* __restrict__ out)         // [65536,128]
{
    __shared__ alignas(16) short At[128 * 128];
    __shared__ alignas(16) short Wt[128 * 128];
    int tid = threadIdx.x;
    int wave = tid >> 6, lane = tid & 63;
    int r = lane & 15, quad = lane >> 4;
    size_t m0 = (size_t)blockIdx.x * 128;

    // staging: 1 issue = 64 lanes x 16B = 4 rows of 256B
    int lrow = lane >> 4;                       // 0..3
    int lslot = lane & 15;                      // 16B slot in row
    #pragma unroll
    for (int j = 0; j < 8; ++j) {
        int row = wave * 32 + j * 4 + lrow;
        int col = ((lslot ^ (row & 7)) << 3);   // pre-swizzled source column
        gld16(bbb + (m0 + row) * BDIM + col, &At[(wave * 32 + j * 4) * 128]);
        gld16(wb + (size_t)row * BDIM + col,  &Wt[(wave * 32 + j * 4) * 128]);
    }

    floatx4 acc[2][8];
    #pragma unroll
    for (int i = 0; i < 2; ++i)
        #pragma unroll
        for (int j = 0; j < 8; ++j) acc[i][j] = floatx4{0.f,0.f,0.f,0.f};

    __syncthreads();   // drains vmcnt before barrier -> LDS tiles ready

    #pragma unroll
    for (int kc = 0; kc < 4; ++kc) {
        int sw = (((kc << 2) + quad) ^ (r & 7)) << 3;
        short8 a0 = *(const short8*)&At[(wave * 32 + r) * 128 + sw];
        short8 a1 = *(const short8*)&At[(wave * 32 + 16 + r) * 128 + sw];
        #pragma unroll
        for (int nj = 0; nj < 8; ++nj) {
            short8 b = *(const short8*)&Wt[(nj * 16 + r) * 128 + sw];
            acc[0][nj] = MFMA(a0, b, acc[0][nj]);
            acc[1][nj] = MFMA(a1, b, acc[1][nj]);
        }
    }

    #pragma unroll
    for (int mi = 0; mi < 2; ++mi) {
        #pragma unroll
        for (int nj = 0; nj < 8; ++nj) {
            int col = nj * 16 + r;
            float bs = bias[col];
            #pragma unroll
            for (int g = 0; g < 4; ++g) {
                size_t row = m0 + wave * 32 + mi * 16 + quad * 4 + g;
                out[row * BDIM + col] = mishf(acc[mi][nj][g] + bs) + rf2bb[(row >> 4) * BDIM + col];
            }
        }
    }
}

extern "C" void kernel_launch(void* const* d_in, const int* in_sizes, int n_in,
                              void* d_out, int out_size, void* d_ws, size_t ws_size,
                              hipStream_t stream) {
    const float* BB    = (const float*)d_in[0];
    const float* RF    = (const float*)d_in[1];
    const float* Wrfbb = (const float*)d_in[2];
    const float* brfbb = (const float*)d_in[3];
    const float* Wrfrf = (const float*)d_in[4];
    const float* brfrf = (const float*)d_in[5];
    const float* Wbbrf = (const float*)d_in[6];
    const float* bbbrf = (const float*)d_in[7];
    const float* Wbbbb = (const float*)d_in[8];
    const float* bbbbb = (const float*)d_in[9];

    float* outBB = (float*)d_out;
    float* outRF = outBB + (size_t)NB * NG * BDIM;

    char* w = (char*)d_ws;
    short* mean_b  = (short*)(w);                  // 4096*128*2    = 1,048,576
    short* rf_b    = (short*)(w + 1048576);        // 4096*1024*2   = 8,388,608
    short* wrfrf_b = (short*)(w + 9437184);        // 1024*1024*2   = 2,097,152
    short* wrfbb_b = (short*)(w + 11534336);       // 128*1024*2    =   262,144
    short* wbbrf_b = (short*)(w + 11796480);       // 1024*128*2    =   262,144
    short* wbbbb_b = (short*)(w + 12058624);       // 128*128*2     =    32,768
    short* bb_b    = (short*)(w + 12091392);       // 65536*128*2   = 16,777,216
    float* rf2bb   = (float*)(w + 28868608);       // 4096*128*4    =  2,097,152
    // total ws: 30,965,760 B

    k_prep <<<1024, 256, 0, stream>>>(BB, RF, Wrfrf, Wrfbb, Wbbrf, Wbbbb,
                                      bb_b, mean_b, rf_b, wrfrf_b, wrfbb_b,
                                      wbbrf_b, wbbbb_b);
    k_newrf<<<512, 256, 0, stream>>>(rf_b, mean_b, wrfrf_b, brfrf, wbbrf_b, bbbrf,
                                     wrfbb_b, brfbb, outRF, rf2bb);
    k_newbb<<<512, 256, 0, stream>>>(bb_b, wbbbb_b, bbbbb, rf2bb, outBB);
}